// Round 2
// baseline (214.672 us; speedup 1.0000x reference)
//
#include <hip/hip_runtime.h>
#include <hip/hip_bf16.h>

// Shapes (fixed by the reference):
//   edges     [E=4096, 2]        int32
//   neigh_idx [N=100000, K=10]   int32
//   features  [N, 256]           f32
//   W1        [128, 256]         f32
//   W2        [128, 128]         f32
//   Wc        [2, 128]           f32
// out = [E, 2] f32
//
// Restructure (all linear ops commute with the neighbor means):
//   z  = features @ W1^T                       (dense GEMM, bf16 MFMA, z stored bf16)
//   h1m[e,p] = mean_k relu( mean_j z[neigh[neigh[edges[e,p]][k]][j]] )
//   out[e]   = (0.5*(h1m[e,0]+h1m[e,1])) @ (Wc@W2)^T

typedef __bf16 bf16x8 __attribute__((ext_vector_type(8)));
typedef float f32x4 __attribute__((ext_vector_type(4)));

#define FEAT 256
#define EMB  128
#define KNB  10
#define BM   128   // gemm M-tile rows

__device__ inline unsigned short f2b(float f) {
  unsigned int u = __float_as_uint(f);
  unsigned int r = (u + 0x7fffu + ((u >> 16) & 1u)) >> 16;  // RNE
  return (unsigned short)r;
}
__device__ inline float b2f(unsigned short s) {
  return __uint_as_float(((unsigned int)s) << 16);
}

// ---- fused setup: blocks 0..127 convert W1 -> bf16; block 128 computes
//      M2 = Wc @ W2  ([2,128] f32) --------------------------------------

__global__ void setup(const float* __restrict__ W1, const float* __restrict__ W2,
                      const float* __restrict__ Wc,
                      unsigned short* __restrict__ w1b, float* __restrict__ M2) {
  const int b = blockIdx.x;
  if (b < 128) {
    int i = b * 256 + threadIdx.x;          // 128*256 == EMB*FEAT exactly
    w1b[i] = f2b(W1[i]);
  } else {
    int t = threadIdx.x, c = t >> 7, d = t & 127;
    float s = 0.f;
    for (int g = 0; g < EMB; ++g) s += Wc[c * EMB + g] * W2[g * EMB + d];
    M2[t] = s;
  }
}

// ---- z = features @ W1^T  (bf16 MFMA, f32 accum, bf16 out) --------------
// block = 512 threads (8 waves), BM=128 row tile. Each wave owns one 16-col
// n-tile; W1 fragments live in VGPRs; A tile staged f32->bf16 in LDS.

__global__ __launch_bounds__(512, 4) void gemm_z(
    const float* __restrict__ feat, const unsigned short* __restrict__ w1b,
    unsigned short* __restrict__ z, int M) {
  __shared__ unsigned short As[BM][FEAT + 8];   // +8 bf16 pad: stride 528B -> 2-way (free)

  const int wid  = threadIdx.x >> 6;   // 0..7  -> n-tile
  const int lane = threadIdx.x & 63;
  const int m0   = blockIdx.x * BM;

  // B fragments: B[k][col] = W1[col][k]; lane holds col=(lane&15), k=kk*32+(lane>>4)*8+i
  bf16x8 bfrag[8];
  {
    const int col = wid * 16 + (lane & 15);
    const int kof = (lane >> 4) * 8;
#pragma unroll
    for (int kk = 0; kk < 8; ++kk)
      bfrag[kk] = *reinterpret_cast<const bf16x8*>(&w1b[col * FEAT + kk * 32 + kof]);
  }

  // stage A tile: BM rows x 256 f32 -> bf16 LDS (zero-pad tail rows)
  const float4* f4 = reinterpret_cast<const float4*>(feat);
  for (int i = threadIdx.x; i < BM * 64; i += 512) {
    int r = i >> 6, c4 = i & 63;
    int row = m0 + r;
    float4 v = make_float4(0.f, 0.f, 0.f, 0.f);
    if (row < M) v = f4[(size_t)row * 64 + c4];
    ushort4 bq;
    bq.x = f2b(v.x); bq.y = f2b(v.y); bq.z = f2b(v.z); bq.w = f2b(v.w);
    *reinterpret_cast<ushort4*>(&As[r][c4 * 4]) = bq;
  }
  __syncthreads();

  f32x4 acc[BM / 16] = {};
  const int arow = lane & 15;
  const int kof  = (lane >> 4) * 8;
#pragma unroll
  for (int mt = 0; mt < BM / 16; ++mt) {
#pragma unroll
    for (int kk = 0; kk < 8; ++kk) {
      bf16x8 a = *reinterpret_cast<const bf16x8*>(&As[mt * 16 + arow][kk * 32 + kof]);
      acc[mt] = __builtin_amdgcn_mfma_f32_16x16x32_bf16(a, bfrag[kk], acc[mt], 0, 0, 0);
    }
  }

  // D layout: col = lane&15, row = (lane>>4)*4 + reg   [m89-verified]
  const int col = wid * 16 + (lane & 15);
#pragma unroll
  for (int mt = 0; mt < BM / 16; ++mt) {
    int rbase = m0 + mt * 16 + (lane >> 4) * 4;
#pragma unroll
    for (int r = 0; r < 4; ++r) {
      int row = rbase + r;
      if (row < M) z[(size_t)row * EMB + col] = f2b(acc[mt][r]);
    }
  }
}

// ---- per-edge aggregation + classifier ----------------------------------
// one block (128 threads = 2 waves) per edge. Wave w owns endpoint p=w;
// lane l owns embed dims {2l, 2l+1} -> every z-row read is one full-row
// 256B wave access (u32/lane), half the memory instructions of v1.

__global__ __launch_bounds__(128) void aggregate(
    const int* __restrict__ edges, const int* __restrict__ nidx,
    const unsigned short* __restrict__ z, const float* __restrict__ M2,
    float* __restrict__ out, int E) {
  __shared__ int   s_idx2[2][KNB];        // 20
  __shared__ int   s_idx1[2][KNB * KNB];  // 200
  __shared__ float s_pm[2][EMB];

  const int e = blockIdx.x;
  const int t = threadIdx.x;
  const int w = t >> 6;        // wave == endpoint p
  const int l = t & 63;

  if (t < 2 * KNB) {
    int p = t / KNB, k = t % KNB;
    int v = edges[e * 2 + p];
    s_idx2[p][k] = nidx[(size_t)v * KNB + k];
  }
  __syncthreads();
  for (int i = t; i < 2 * KNB * KNB; i += 128) {
    int p = i / 100, r = i % 100;
    s_idx1[p][r] = nidx[(size_t)s_idx2[p][r / KNB] * KNB + (r % KNB)];
  }
  __syncthreads();

  float pooled0 = 0.f, pooled1 = 0.f;
#pragma unroll
  for (int k = 0; k < KNB; ++k) {
    float a0 = 0.f, a1 = 0.f;
#pragma unroll
    for (int j = 0; j < KNB; ++j) {
      int u = s_idx1[w][k * KNB + j];
      unsigned int q = *reinterpret_cast<const unsigned int*>(&z[(size_t)u * EMB + 2 * l]);
      a0 += b2f((unsigned short)(q & 0xffffu));
      a1 += b2f((unsigned short)(q >> 16));
    }
    pooled0 += fmaxf(a0 * 0.1f, 0.f);    // relu(mean_j)
    pooled1 += fmaxf(a1 * 0.1f, 0.f);
  }
  s_pm[w][2 * l]     = pooled0 * 0.1f;   // mean_k
  s_pm[w][2 * l + 1] = pooled1 * 0.1f;
  __syncthreads();

  if (w == 0) {
    int d0 = 2 * l, d1 = 2 * l + 1;
    float p0 = 0.5f * (s_pm[0][d0] + s_pm[1][d0]);
    float p1 = 0.5f * (s_pm[0][d1] + s_pm[1][d1]);
    float s0 = p0 * M2[d0]       + p1 * M2[d1];
    float s1 = p0 * M2[EMB + d0] + p1 * M2[EMB + d1];
#pragma unroll
    for (int off = 32; off > 0; off >>= 1) {
      s0 += __shfl_down(s0, off);
      s1 += __shfl_down(s1, off);
    }
    if (l == 0) { out[e * 2 + 0] = s0; out[e * 2 + 1] = s1; }
  }
}

// ---- launcher -----------------------------------------------------------

extern "C" void kernel_launch(void* const* d_in, const int* in_sizes, int n_in,
                              void* d_out, int out_size, void* d_ws, size_t ws_size,
                              hipStream_t stream) {
  const int*   edges = (const int*)d_in[0];
  const int*   nidx  = (const int*)d_in[1];
  const float* feat  = (const float*)d_in[2];
  const float* W1    = (const float*)d_in[3];
  const float* W2    = (const float*)d_in[4];
  const float* Wc    = (const float*)d_in[5];
  float* out = (float*)d_out;

  const int N = in_sizes[2] / FEAT;   // 100000
  const int E = in_sizes[0] / 2;      // 4096

  char* ws = (char*)d_ws;
  unsigned short* z   = (unsigned short*)ws;                       // N*128 bf16
  size_t zbytes = (size_t)N * EMB * sizeof(unsigned short);
  unsigned short* w1b = (unsigned short*)(ws + zbytes);            // 128*256 bf16
  float* M2 = (float*)(ws + zbytes + (size_t)EMB * FEAT * sizeof(unsigned short));

  setup  <<<129, 256, 0, stream>>>(W1, W2, Wc, w1b, M2);
  gemm_z <<<(N + BM - 1) / BM, 512, 0, stream>>>(feat, w1b, z, N);
  aggregate<<<E, 128, 0, stream>>>(edges, nidx, z, M2, out, E);
}

// Round 5
// 211.242 us; speedup vs baseline: 1.0162x; 1.0162x over previous
//
#include <hip/hip_runtime.h>
#include <hip/hip_bf16.h>

// Shapes (fixed by the reference):
//   edges     [E=4096, 2]        int32
//   neigh_idx [N=100000, K=10]   int32
//   features  [N, 256]           f32
//   W1        [128, 256]         f32
//   W2        [128, 128]         f32
//   Wc        [2, 128]           f32
// out = [E, 2] f32
//
// Restructure (all linear ops commute with the neighbor means):
//   z  = features @ W1^T                       (dense GEMM, bf16 MFMA, z stored bf16)
//   h1m[e,p] = mean_k relu( mean_j z[neigh[neigh[edges[e,p]][k]][j]] )
//   out[e]   = (0.5*(h1m[e,0]+h1m[e,1])) @ (Wc@W2)^T
//
// R3 kernel, third submission (two GPU-acquisition timeouts): setup kernel
//     removed (W1 fragments loaded f32-direct from L2 per wave; M2 computed
//     by one extra gemm_z block). aggregate: paired-row uint2 gathers (2
//     z-rows per wave-load, 50 loads/endpoint instead of 100) to double
//     memory-level parallelism on the latency-bound gather loop.

typedef __bf16 bf16x8 __attribute__((ext_vector_type(8)));
typedef float f32x4 __attribute__((ext_vector_type(4)));

#define FEAT 256
#define EMB  128
#define KNB  10
#define BM   128   // gemm M-tile rows

__device__ inline unsigned short f2b(float f) {
  unsigned int u = __float_as_uint(f);
  unsigned int r = (u + 0x7fffu + ((u >> 16) & 1u)) >> 16;  // RNE
  return (unsigned short)r;
}
__device__ inline float b2f(unsigned int s) {
  return __uint_as_float(s << 16);
}

// ---- z = features @ W1^T  (bf16 MFMA, f32 accum, bf16 out) --------------
// block = 512 threads (8 waves), BM=128 row tile. Each wave owns one 16-col
// n-tile; W1 fragments converted f32->bf16 in registers (W1 stays L2-hot);
// A tile staged f32->bf16 in LDS. Last block computes M2 = Wc@W2 instead.

__global__ __launch_bounds__(512, 4) void gemm_z(
    const float* __restrict__ feat, const float* __restrict__ W1,
    const float* __restrict__ W2, const float* __restrict__ Wc,
    unsigned short* __restrict__ z, float* __restrict__ M2, int M) {
  __shared__ unsigned short As[BM][FEAT + 8];   // +8 bf16 pad

  if (blockIdx.x == gridDim.x - 1) {
    // M2 = Wc @ W2  -> [2,128] f32
    int t = threadIdx.x;
    if (t < 256) {
      int c = t >> 7, d = t & 127;
      float s = 0.f;
      for (int g = 0; g < EMB; ++g) s += Wc[c * EMB + g] * W2[g * EMB + d];
      M2[t] = s;
    }
    return;
  }

  const int wid  = threadIdx.x >> 6;   // 0..7  -> n-tile
  const int lane = threadIdx.x & 63;
  const int m0   = blockIdx.x * BM;

  // B fragments: B[k][col] = W1[col][k]; lane holds col=(lane&15), k=kk*32+(lane>>4)*8+i
  bf16x8 bfrag[8];
  {
    const int col = wid * 16 + (lane & 15);
    const int kof = (lane >> 4) * 8;
#pragma unroll
    for (int kk = 0; kk < 8; ++kk) {
      const float* src = &W1[col * FEAT + kk * 32 + kof];
      float4 lo = *reinterpret_cast<const float4*>(src);
      float4 hi = *reinterpret_cast<const float4*>(src + 4);
      union { unsigned short s[8]; bf16x8 v; } cvt;
      cvt.s[0] = f2b(lo.x); cvt.s[1] = f2b(lo.y); cvt.s[2] = f2b(lo.z); cvt.s[3] = f2b(lo.w);
      cvt.s[4] = f2b(hi.x); cvt.s[5] = f2b(hi.y); cvt.s[6] = f2b(hi.z); cvt.s[7] = f2b(hi.w);
      bfrag[kk] = cvt.v;
    }
  }

  // stage A tile: BM rows x 256 f32 -> bf16 LDS (zero-pad tail rows)
  const float4* f4 = reinterpret_cast<const float4*>(feat);
  for (int i = threadIdx.x; i < BM * 64; i += 512) {
    int r = i >> 6, c4 = i & 63;
    int row = m0 + r;
    float4 v = make_float4(0.f, 0.f, 0.f, 0.f);
    if (row < M) v = f4[(size_t)row * 64 + c4];
    ushort4 bq;
    bq.x = f2b(v.x); bq.y = f2b(v.y); bq.z = f2b(v.z); bq.w = f2b(v.w);
    *reinterpret_cast<ushort4*>(&As[r][c4 * 4]) = bq;
  }
  __syncthreads();

  f32x4 acc[BM / 16] = {};
  const int arow = lane & 15;
  const int kof  = (lane >> 4) * 8;
#pragma unroll
  for (int mt = 0; mt < BM / 16; ++mt) {
#pragma unroll
    for (int kk = 0; kk < 8; ++kk) {
      bf16x8 a = *reinterpret_cast<const bf16x8*>(&As[mt * 16 + arow][kk * 32 + kof]);
      acc[mt] = __builtin_amdgcn_mfma_f32_16x16x32_bf16(a, bfrag[kk], acc[mt], 0, 0, 0);
    }
  }

  // D layout: col = lane&15, row = (lane>>4)*4 + reg   [m89-verified]
  const int col = wid * 16 + (lane & 15);
#pragma unroll
  for (int mt = 0; mt < BM / 16; ++mt) {
    int rbase = m0 + mt * 16 + (lane >> 4) * 4;
#pragma unroll
    for (int r = 0; r < 4; ++r) {
      int row = rbase + r;
      if (row < M) z[(size_t)row * EMB + col] = f2b(acc[mt][r]);
    }
  }
}

// ---- per-edge aggregation + classifier ----------------------------------
// one block (128 threads = 2 waves) per edge; wave w = endpoint p.
// Paired-row gathers: lane half h=l>>5 covers row 2j+h, the 32 lanes of a
// half each load uint2 (4 bf16 dims) -> one wave-load covers TWO z-rows
// (512B). 50 loads per endpoint (was 100); parity halves combined once per
// k with 4 shfl_xor(32) before the relu.

__global__ __launch_bounds__(128) void aggregate(
    const int* __restrict__ edges, const int* __restrict__ nidx,
    const unsigned short* __restrict__ z, const float* __restrict__ M2,
    float* __restrict__ out, int E) {
  __shared__ int   s_idx2[2][KNB];        // 20
  __shared__ int   s_idx1[2][KNB * KNB];  // 200
  __shared__ float s_pm[2][EMB];

  const int e = blockIdx.x;
  const int t = threadIdx.x;
  const int w = t >> 6;        // wave == endpoint p
  const int l = t & 63;
  const int h = l >> 5;        // row-parity half
  const int q = l & 31;        // uint2 slot within row (dims 4q..4q+3)

  if (t < 2 * KNB) {
    int p = t / KNB, k = t % KNB;
    int v = edges[e * 2 + p];
    s_idx2[p][k] = nidx[(size_t)v * KNB + k];
  }
  __syncthreads();
  for (int i = t; i < 2 * KNB * KNB; i += 128) {
    int p = i / 100, r = i % 100;
    s_idx1[p][r] = nidx[(size_t)s_idx2[p][r / KNB] * KNB + (r % KNB)];
  }
  __syncthreads();

  float pooled[4] = {0.f, 0.f, 0.f, 0.f};
#pragma unroll
  for (int k = 0; k < KNB; ++k) {
    float a[4] = {0.f, 0.f, 0.f, 0.f};
#pragma unroll
    for (int jp = 0; jp < KNB / 2; ++jp) {
      int u = s_idx1[w][k * KNB + jp * 2 + h];
      uint2 v = *reinterpret_cast<const uint2*>(&z[(size_t)u * EMB + q * 4]);
      a[0] += b2f(v.x & 0xffffu); a[1] += b2f(v.x >> 16);
      a[2] += b2f(v.y & 0xffffu); a[3] += b2f(v.y >> 16);
    }
#pragma unroll
    for (int c = 0; c < 4; ++c) {
      float s = a[c] + __shfl_xor(a[c], 32);   // combine row parities: 10-row sum
      pooled[c] += fmaxf(s * 0.1f, 0.f);       // relu(mean_j)
    }
  }
  if (h == 0) {
#pragma unroll
    for (int c = 0; c < 4; ++c) s_pm[w][q * 4 + c] = pooled[c] * 0.1f;  // mean_k
  }
  __syncthreads();

  if (w == 0) {
    int d0 = 2 * l, d1 = 2 * l + 1;
    float p0 = 0.5f * (s_pm[0][d0] + s_pm[1][d0]);
    float p1 = 0.5f * (s_pm[0][d1] + s_pm[1][d1]);
    float s0 = p0 * M2[d0]       + p1 * M2[d1];
    float s1 = p0 * M2[EMB + d0] + p1 * M2[EMB + d1];
#pragma unroll
    for (int off = 32; off > 0; off >>= 1) {
      s0 += __shfl_down(s0, off);
      s1 += __shfl_down(s1, off);
    }
    if (l == 0) { out[e * 2 + 0] = s0; out[e * 2 + 1] = s1; }
  }
}

// ---- launcher -----------------------------------------------------------

extern "C" void kernel_launch(void* const* d_in, const int* in_sizes, int n_in,
                              void* d_out, int out_size, void* d_ws, size_t ws_size,
                              hipStream_t stream) {
  const int*   edges = (const int*)d_in[0];
  const int*   nidx  = (const int*)d_in[1];
  const float* feat  = (const float*)d_in[2];
  const float* W1    = (const float*)d_in[3];
  const float* W2    = (const float*)d_in[4];
  const float* Wc    = (const float*)d_in[5];
  float* out = (float*)d_out;

  const int N = in_sizes[2] / FEAT;   // 100000
  const int E = in_sizes[0] / 2;      // 4096

  char* ws = (char*)d_ws;
  unsigned short* z = (unsigned short*)ws;                         // N*128 bf16
  float* M2 = (float*)(ws + (size_t)N * EMB * sizeof(unsigned short));

  int mtiles = (N + BM - 1) / BM;
  gemm_z <<<mtiles + 1, 512, 0, stream>>>(feat, W1, W2, Wc, z, M2, N);
  aggregate<<<E, 128, 0, stream>>>(edges, nidx, z, M2, out, E);
}